// Round 3
// baseline (1578.676 us; speedup 1.0000x reference)
//
#include <hip/hip_runtime.h>

#define NT 128      // num tags
#define SEQ 1024    // sequence length
#define NB 256      // batch

// ONE WAVE per batch element. 256 blocks x 64 threads.
// Lane l owns output columns c0=2l, c1=2l+1 and keeps both full E columns
// (prob domain, fp32) in registers: 256 VGPRs. __launch_bounds__(64, 1)
// (min 1 wave/EU) is REQUIRED: without it the compiler caps at ~152 VGPRs
// and spills E to scratch (R2 regression: 1439us, VGPR_Count=152).
// No __syncthreads in the scan: the only cross-lane traffic is the p vector
// through wave-private LDS; per-wave DS ops are in-order (lgkmcnt).
__global__ __launch_bounds__(64, 1) void crf_scan_kernel(
    const float* __restrict__ emissions,    // [B,S,T]
    const float* __restrict__ masks,        // [B,S]
    const int*   __restrict__ tags,         // [B,S]
    const float* __restrict__ transitions,  // [T,T] (log domain)
    const float* __restrict__ start_t,      // [T]
    const float* __restrict__ end_t,        // [T]
    float* __restrict__ out_per_batch)      // [B]
{
    const int b  = blockIdx.x;
    const int l  = threadIdx.x;          // 0..63
    const int c0 = 2 * l;
    const int c1 = 2 * l + 1;

    __shared__ float p_s[NT];            // scaled probabilities
    __shared__ float msk_s[SEQ];

    // ---- E columns into registers (prob domain) ----
    float2 E2[NT];                       // E2[i] = {exp(T[i][c0]), exp(T[i][c1])}
    #pragma unroll
    for (int i = 0; i < NT; ++i) {
        float2 tv = *(const float2*)&transitions[i * NT + c0];
        E2[i].x = __expf(tv.x);
        E2[i].y = __expf(tv.y);
    }

    // masks into LDS (same wave writes and reads -> no barrier needed)
    for (int s = l; s < SEQ; s += 64)
        msk_s[s] = masks[b * SEQ + s];

    // ---- init: p = exp(start_transitions), offset = 0 ----
    float cur0 = __expf(start_t[c0]);
    float cur1 = __expf(start_t[c1]);
    *(float2*)&p_s[c0] = make_float2(cur0, cur1);
    float offset = 0.0f;

    const float* eb = emissions + (size_t)b * SEQ * NT;

    // emission pipeline: ex = exp(em[s]) ready, em1 = raw em[s+1], prefetch s+2
    float2 em0 = *(const float2*)&eb[(size_t)0 * NT + c0];
    float2 em1 = *(const float2*)&eb[(size_t)1 * NT + c0];
    float2 ex;
    ex.x = __expf(em0.x);
    ex.y = __expf(em0.y);

    const float4* p4 = (const float4*)p_s;

    for (int s = 0; s < SEQ; ++s) {
        // prefetch emission 2 steps ahead (covers HBM latency)
        int spre = (s + 2 < SEQ) ? s + 2 : SEQ - 1;
        float2 em2 = *(const float2*)&eb[(size_t)spre * NT + c0];

        // Renorm max: computed from the SAME p the matvec is about to read
        // (cur regs == p_s vector), so the 6-stage shuffle chain overlaps the
        // FMA block below instead of sitting on the critical path.
        bool renorm = (s & 3) == 0;
        float m = 0.0f;
        if (renorm) {
            m = fmaxf(cur0, cur1);
            #pragma unroll
            for (int off = 32; off; off >>= 1)
                m = fmaxf(m, __shfl_xor(m, off));
        }

        // matvec: v_j = sum_i p_i * E[i][j], two columns per lane.
        // p read as all-lanes-same-address float4 broadcasts (conflict-free);
        // float2 accumulators bait v_pk_fma_f32.
        float2 a0 = {0.f, 0.f}, a1 = {0.f, 0.f}, a2 = {0.f, 0.f}, a3 = {0.f, 0.f};
        #pragma unroll
        for (int c = 0; c < 32; ++c) {
            float4 pv = p4[c];
            a0.x += pv.x * E2[4*c+0].x;  a0.y += pv.x * E2[4*c+0].y;
            a1.x += pv.y * E2[4*c+1].x;  a1.y += pv.y * E2[4*c+1].y;
            a2.x += pv.z * E2[4*c+2].x;  a2.y += pv.z * E2[4*c+2].y;
            a3.x += pv.w * E2[4*c+3].x;  a3.y += pv.w * E2[4*c+3].y;
        }
        float v0 = ((a0.x + a1.x) + (a2.x + a3.x)) * ex.x;
        float v1 = ((a0.y + a1.y) + (a2.y + a3.y)) * ex.y;

        bool upd = msk_s[s] > 0.0f;      // wave-uniform
        if (upd) { cur0 = v0; cur1 = v1; }

        // apply (stale-by-one-step scale: identity-preserving, window <= e^60)
        if (renorm) {
            float inv = 1.0f / m;
            cur0 *= inv; cur1 *= inv;
            offset += __logf(m);
        }
        *(float2*)&p_s[c0] = make_float2(cur0, cur1);

        // rotate emission pipeline (exp computed off the critical path)
        ex.x = __expf(em1.x);
        ex.y = __expf(em1.y);
        em1 = em2;
    }

    // ---- log_z = offset + log( sum_j p_j * exp(end_j) ) ----
    float term = cur0 * __expf(end_t[c0]) + cur1 * __expf(end_t[c1]);
    #pragma unroll
    for (int off = 32; off; off >>= 1)
        term += __shfl_xor(term, off);
    float log_z = offset + __logf(term);

    // ---- gold-path score (single wave, 16 s-iters/lane) ----
    const int tb = b * SEQ;
    float sc = 0.0f, sm = 0.0f;
    for (int s = l; s < SEQ; s += 64) {
        float m = msk_s[s];
        sm += m;
        if (s < SEQ - 1) {
            int tg  = tags[tb + s];
            int tg1 = tags[tb + s + 1];
            sc += eb[(size_t)s * NT + tg] * m;
            sc += transitions[tg * NT + tg1] * msk_s[s + 1];
        }
    }
    #pragma unroll
    for (int off = 32; off; off >>= 1) {
        sc += __shfl_xor(sc, off);
        sm += __shfl_xor(sm, off);
    }

    if (l == 0) {
        int tg0 = tags[tb];
        int tgl = tags[tb + SEQ - 1];
        sc += start_t[tg0];
        int last_ix = (int)fmaxf(sm - 1.0f, 0.0f);
        float ml = msk_s[SEQ - 1];
        sc += eb[(size_t)last_ix * NT + tgl] * ml;
        sc += end_t[tgl] * ml;
        out_per_batch[b] = log_z - sc;
    }
}

// mean over batch -> scalar output
__global__ void crf_reduce_kernel(const float* __restrict__ pb, float* __restrict__ out)
{
    float v = pb[threadIdx.x];   // 256 threads, one per batch
    #pragma unroll
    for (int off = 32; off; off >>= 1)
        v += __shfl_xor(v, off);
    __shared__ float s4[4];
    if ((threadIdx.x & 63) == 0) s4[threadIdx.x >> 6] = v;
    __syncthreads();
    if (threadIdx.x == 0)
        out[0] = (s4[0] + s4[1] + s4[2] + s4[3]) * (1.0f / 256.0f);
}

extern "C" void kernel_launch(void* const* d_in, const int* in_sizes, int n_in,
                              void* d_out, int out_size, void* d_ws, size_t ws_size,
                              hipStream_t stream) {
    const float* emissions   = (const float*)d_in[0];
    const float* masks       = (const float*)d_in[1];
    const int*   tags        = (const int*)  d_in[2];
    const float* transitions = (const float*)d_in[3];
    const float* start_t     = (const float*)d_in[4];
    const float* end_t       = (const float*)d_in[5];
    float* per_batch = (float*)d_ws;

    crf_scan_kernel<<<NB, 64, 0, stream>>>(emissions, masks, tags, transitions,
                                           start_t, end_t, per_batch);
    crf_reduce_kernel<<<1, 256, 0, stream>>>(per_batch, (float*)d_out);
}

// Round 4
// 785.450 us; speedup vs baseline: 2.0099x; 2.0099x over previous
//
#include <hip/hip_runtime.h>

#define NT 128      // num tags
#define SEQ 1024    // sequence length
#define NB 256      // batch

typedef _Float16 half2v __attribute__((ext_vector_type(2)));

// ONE WAVE per batch element. 256 blocks x 64 threads. Lane l owns output
// columns c0=2l, c1=2l+1. E (prob domain) is held in registers as f16 pairs:
// E0/E1[64] half2 = 128 VGPRs total — fits the 256-VGPR arch limit (fp32
// storage needs 256 regs for E alone and ALWAYS spills: R2/R3 at 1449us,
// VGPR_Count=152 with scratch). Matvec via v_dot2_f32_f16 (fp32 accumulate).
// p lives in LDS as packed f16 (renormed every step so max ~< 7e3 << f16 max).
// No __syncthreads in the scan: only cross-lane traffic is p through
// wave-private LDS; per-wave DS ops are in-order.
__global__ __launch_bounds__(64, 1) void crf_scan_kernel(
    const float* __restrict__ emissions,    // [B,S,T]
    const float* __restrict__ masks,        // [B,S]
    const int*   __restrict__ tags,         // [B,S]
    const float* __restrict__ transitions,  // [T,T] (log domain)
    const float* __restrict__ start_t,      // [T]
    const float* __restrict__ end_t,        // [T]
    float* __restrict__ out_per_batch)      // [B]
{
    const int b  = blockIdx.x;
    const int l  = threadIdx.x;          // 0..63
    const int c0 = 2 * l;
    const int c1 = 2 * l + 1;

    __shared__ unsigned int p_h[64];     // packed f16 pairs: p_h[r] = (p[2r], p[2r+1])
    __shared__ float msk_s[SEQ];

    // ---- E columns into registers, f16 pairs along the row (i) dim ----
    // E0[r] = (exp(T[2r][c0]), exp(T[2r+1][c0])), E1 same for c1.
    half2v E0[64], E1[64];
    #pragma unroll
    for (int r = 0; r < 64; ++r) {
        float2 ta = *(const float2*)&transitions[(2 * r)     * NT + c0];
        float2 tb = *(const float2*)&transitions[(2 * r + 1) * NT + c0];
        E0[r] = half2v{(_Float16)__expf(ta.x), (_Float16)__expf(tb.x)};
        E1[r] = half2v{(_Float16)__expf(ta.y), (_Float16)__expf(tb.y)};
    }

    // masks into LDS (same wave writes and reads -> no barrier needed)
    for (int s = l; s < SEQ; s += 64)
        msk_s[s] = masks[b * SEQ + s];

    // ---- init: p = exp(start_transitions), offset = 0 ----
    float cur0 = __expf(start_t[c0]);
    float cur1 = __expf(start_t[c1]);
    p_h[l] = __builtin_bit_cast(unsigned int, __builtin_amdgcn_cvt_pkrtz(cur0, cur1));
    float offset = 0.0f;

    const float* eb = emissions + (size_t)b * SEQ * NT;

    // emission pipeline: ex = exp(em[s]) ready, em1 = raw em[s+1], prefetch s+2
    float2 em0 = *(const float2*)&eb[(size_t)0 * NT + c0];
    float2 em1 = *(const float2*)&eb[(size_t)1 * NT + c0];
    float2 ex;
    ex.x = __expf(em0.x);
    ex.y = __expf(em0.y);

    const uint4* p4r = (const uint4*)p_h;   // 16 x (4 dwords = 8 p values)

    for (int s = 0; s < SEQ; ++s) {
        // prefetch emission 2 steps ahead (covers HBM latency)
        int spre = (s + 2 < SEQ) ? s + 2 : SEQ - 1;
        float2 em2 = *(const float2*)&eb[(size_t)spre * NT + c0];

        // Renorm max from the SAME p the matvec reads (cur regs == stored p),
        // so the 6-stage shuffle chain overlaps the dot block below.
        float m = fmaxf(cur0, cur1);
        #pragma unroll
        for (int off = 32; off; off >>= 1)
            m = fmaxf(m, __shfl_xor(m, off));

        // matvec: v_j = sum_i p_i * E[i][j], two columns per lane.
        // p read as all-lanes-same-address uint4 broadcasts (conflict-free);
        // v_dot2_f32_f16: 2 f16 MACs with fp32 accumulate per instruction.
        float A0 = 0.f, A1 = 0.f, A2 = 0.f, A3 = 0.f;
        float B0 = 0.f, B1 = 0.f, B2 = 0.f, B3 = 0.f;
        #pragma unroll
        for (int c = 0; c < 16; ++c) {
            uint4 q = p4r[c];
            half2v p0 = __builtin_bit_cast(half2v, q.x);
            half2v p1 = __builtin_bit_cast(half2v, q.y);
            half2v p2 = __builtin_bit_cast(half2v, q.z);
            half2v p3 = __builtin_bit_cast(half2v, q.w);
            A0 = __builtin_amdgcn_fdot2(p0, E0[4*c+0], A0, false);
            B0 = __builtin_amdgcn_fdot2(p0, E1[4*c+0], B0, false);
            A1 = __builtin_amdgcn_fdot2(p1, E0[4*c+1], A1, false);
            B1 = __builtin_amdgcn_fdot2(p1, E1[4*c+1], B1, false);
            A2 = __builtin_amdgcn_fdot2(p2, E0[4*c+2], A2, false);
            B2 = __builtin_amdgcn_fdot2(p2, E1[4*c+2], B2, false);
            A3 = __builtin_amdgcn_fdot2(p3, E0[4*c+3], A3, false);
            B3 = __builtin_amdgcn_fdot2(p3, E1[4*c+3], B3, false);
        }
        float v0 = ((A0 + A1) + (A2 + A3)) * ex.x;
        float v1 = ((B0 + B1) + (B2 + B3)) * ex.y;

        if (msk_s[s] > 0.0f) { cur0 = v0; cur1 = v1; }  // wave-uniform

        // every-step renorm with stale (pre-update) max + /256 guard:
        // stored max <= 128*e^{maxT}*e^{maxEm}/256 ~ 7e3 < f16 max 65504.
        float inv = 0.00390625f / m;
        cur0 *= inv; cur1 *= inv;
        offset += __logf(m) + 5.545177444479562f;   // + log(256)

        p_h[l] = __builtin_bit_cast(unsigned int, __builtin_amdgcn_cvt_pkrtz(cur0, cur1));

        // rotate emission pipeline (exp computed off the critical path)
        ex.x = __expf(em1.x);
        ex.y = __expf(em1.y);
        em1 = em2;
    }

    // ---- log_z = offset + log( sum_j p_j * exp(end_j) ) ----
    // cur0/cur1 are fp32 and consistent with offset (scaled together).
    float term = cur0 * __expf(end_t[c0]) + cur1 * __expf(end_t[c1]);
    #pragma unroll
    for (int off = 32; off; off >>= 1)
        term += __shfl_xor(term, off);
    float log_z = offset + __logf(term);

    // ---- gold-path score (single wave, 16 s-iters/lane) ----
    const int tb = b * SEQ;
    float sc = 0.0f, sm = 0.0f;
    for (int s = l; s < SEQ; s += 64) {
        float m = msk_s[s];
        sm += m;
        if (s < SEQ - 1) {
            int tg  = tags[tb + s];
            int tg1 = tags[tb + s + 1];
            sc += eb[(size_t)s * NT + tg] * m;
            sc += transitions[tg * NT + tg1] * msk_s[s + 1];
        }
    }
    #pragma unroll
    for (int off = 32; off; off >>= 1) {
        sc += __shfl_xor(sc, off);
        sm += __shfl_xor(sm, off);
    }

    if (l == 0) {
        int tg0 = tags[tb];
        int tgl = tags[tb + SEQ - 1];
        sc += start_t[tg0];
        int last_ix = (int)fmaxf(sm - 1.0f, 0.0f);
        float ml = msk_s[SEQ - 1];
        sc += eb[(size_t)last_ix * NT + tgl] * ml;
        sc += end_t[tgl] * ml;
        out_per_batch[b] = log_z - sc;
    }
}

// mean over batch -> scalar output
__global__ void crf_reduce_kernel(const float* __restrict__ pb, float* __restrict__ out)
{
    float v = pb[threadIdx.x];   // 256 threads, one per batch
    #pragma unroll
    for (int off = 32; off; off >>= 1)
        v += __shfl_xor(v, off);
    __shared__ float s4[4];
    if ((threadIdx.x & 63) == 0) s4[threadIdx.x >> 6] = v;
    __syncthreads();
    if (threadIdx.x == 0)
        out[0] = (s4[0] + s4[1] + s4[2] + s4[3]) * (1.0f / 256.0f);
}

extern "C" void kernel_launch(void* const* d_in, const int* in_sizes, int n_in,
                              void* d_out, int out_size, void* d_ws, size_t ws_size,
                              hipStream_t stream) {
    const float* emissions   = (const float*)d_in[0];
    const float* masks       = (const float*)d_in[1];
    const int*   tags        = (const int*)  d_in[2];
    const float* transitions = (const float*)d_in[3];
    const float* start_t     = (const float*)d_in[4];
    const float* end_t       = (const float*)d_in[5];
    float* per_batch = (float*)d_ws;

    crf_scan_kernel<<<NB, 64, 0, stream>>>(emissions, masks, tags, transitions,
                                           start_t, end_t, per_batch);
    crf_reduce_kernel<<<1, 256, 0, stream>>>(per_batch, (float*)d_out);
}

// Round 5
// 710.275 us; speedup vs baseline: 2.2226x; 1.1058x over previous
//
#include <hip/hip_runtime.h>

#define NT 128      // num tags
#define SEQ 1024    // sequence length
#define NB 256      // batch

typedef _Float16 half2v __attribute__((ext_vector_type(2)));

// One DPP max step on the VALU pipe (no DS/lgkmcnt involvement).
#define DPP_MAX_STEP(x, ctrl)                                                   \
    fmaxf((x), __builtin_bit_cast(float, __builtin_amdgcn_update_dpp(           \
        __builtin_bit_cast(int, (x)), __builtin_bit_cast(int, (x)),             \
        (ctrl), 0xf, 0xf, false)))

__device__ __forceinline__ float wave_max_dpp(float x) {
    x = DPP_MAX_STEP(x, 0x111);   // row_shr:1
    x = DPP_MAX_STEP(x, 0x112);   // row_shr:2
    x = DPP_MAX_STEP(x, 0x114);   // row_shr:4
    x = DPP_MAX_STEP(x, 0x118);   // row_shr:8
    x = DPP_MAX_STEP(x, 0x142);   // row_bcast:15
    x = DPP_MAX_STEP(x, 0x143);   // row_bcast:31
    // lane 63 now holds the wave max; broadcast as wave-uniform SGPR value
    return __builtin_bit_cast(float, __builtin_amdgcn_readlane(
        __builtin_bit_cast(int, x), 63));
}

// ONE WAVE per batch element. 256 blocks x 64 threads. Lane l owns output
// columns c0=2l, c1=2l+1. E (prob domain) in registers as f16 pairs (128
// VGPRs). Matvec via v_dot2_f32_f16. p in LDS as packed f16, max-normalized
// every step with the scale FOLDED INTO the next step's emission factor so
// the DPP-max/rcp/log chain is off the store->read critical path.
// No __syncthreads in the scan (single wave; in-order DS pipe).
__global__ __launch_bounds__(64, 1) void crf_scan_kernel(
    const float* __restrict__ emissions,    // [B,S,T]
    const float* __restrict__ masks,        // [B,S]
    const int*   __restrict__ tags,         // [B,S]
    const float* __restrict__ transitions,  // [T,T] (log domain)
    const float* __restrict__ start_t,      // [T]
    const float* __restrict__ end_t,        // [T]
    float* __restrict__ out_per_batch)      // [B]
{
    const int b  = blockIdx.x;
    const int l  = threadIdx.x;          // 0..63
    const int c0 = 2 * l;
    const int c1 = 2 * l + 1;

    __shared__ unsigned int p_h[64];     // packed f16 pairs: (p[2r], p[2r+1])
    __shared__ float msk_s[SEQ];

    // ---- E columns into registers, f16 pairs along the row (i) dim ----
    half2v E0[64], E1[64];
    #pragma unroll
    for (int r = 0; r < 64; ++r) {
        float2 ta = *(const float2*)&transitions[(2 * r)     * NT + c0];
        float2 tb = *(const float2*)&transitions[(2 * r + 1) * NT + c0];
        E0[r] = half2v{(_Float16)__expf(ta.x), (_Float16)__expf(tb.x)};
        E1[r] = half2v{(_Float16)__expf(ta.y), (_Float16)__expf(tb.y)};
    }

    // masks into LDS (same wave writes then reads -> in-order DS, no barrier)
    for (int s = l; s < SEQ; s += 64)
        msk_s[s] = masks[b * SEQ + s];

    // ---- init: P = exp(start), offset = 0 ----
    float cur0 = __expf(start_t[c0]);
    float cur1 = __expf(start_t[c1]);
    p_h[l] = __builtin_bit_cast(unsigned int, __builtin_amdgcn_cvt_pkrtz(cur0, cur1));
    float offset = 0.0f;

    // scale for the first step, folded into ex
    float mx  = wave_max_dpp(fmaxf(cur0, cur1));
    float inv = __builtin_amdgcn_rcpf(256.0f * mx);
    float offadd = __logf(mx) + 5.545177444479562f;   // log(256*mx)

    const float* eb = emissions + (size_t)b * SEQ * NT;

    // emission pipeline: ex = exp(em[s]) * inv ready; em1 = raw em[s+1]
    float2 em0 = *(const float2*)&eb[(size_t)0 * NT + c0];
    float2 em1 = *(const float2*)&eb[(size_t)1 * NT + c0];
    float2 ex;
    ex.x = __expf(em0.x) * inv;
    ex.y = __expf(em0.y) * inv;

    float mcur = msk_s[0];               // mask for step s (preloaded)

    const uint4* p4r = (const uint4*)p_h;

    for (int s = 0; s < SEQ; ++s) {
        // prefetch emission 2 steps ahead (covers HBM latency)
        int spre = (s + 2 < SEQ) ? s + 2 : SEQ - 1;
        float2 em2 = *(const float2*)&eb[(size_t)spre * NT + c0];

        // matvec: v_j = (sum_i P_i E[i][j]) * exp(em_j) * inv_{prev}
        // p read as all-lanes-same-address uint4 broadcasts (conflict-free).
        float A0 = 0.f, A1 = 0.f, A2 = 0.f, A3 = 0.f;
        float B0 = 0.f, B1 = 0.f, B2 = 0.f, B3 = 0.f;
        #pragma unroll
        for (int c = 0; c < 16; ++c) {
            uint4 q = p4r[c];
            half2v p0 = __builtin_bit_cast(half2v, q.x);
            half2v p1 = __builtin_bit_cast(half2v, q.y);
            half2v p2 = __builtin_bit_cast(half2v, q.z);
            half2v p3 = __builtin_bit_cast(half2v, q.w);
            A0 = __builtin_amdgcn_fdot2(p0, E0[4*c+0], A0, false);
            B0 = __builtin_amdgcn_fdot2(p0, E1[4*c+0], B0, false);
            A1 = __builtin_amdgcn_fdot2(p1, E0[4*c+1], A1, false);
            B1 = __builtin_amdgcn_fdot2(p1, E1[4*c+1], B1, false);
            A2 = __builtin_amdgcn_fdot2(p2, E0[4*c+2], A2, false);
            B2 = __builtin_amdgcn_fdot2(p2, E1[4*c+2], B2, false);
            A3 = __builtin_amdgcn_fdot2(p3, E0[4*c+3], A3, false);
            B3 = __builtin_amdgcn_fdot2(p3, E1[4*c+3], B3, false);
        }
        float v0 = ((A0 + A1) + (A2 + A3)) * ex.x;
        float v1 = ((B0 + B1) + (B2 + B3)) * ex.y;

        // accept/reject (wave-uniform), account the scale we folded into ex
        bool upd = mcur > 0.0f;
        if (upd) { cur0 = v0; cur1 = v1; offset += offadd; }

        // store ASAP: next iteration's 16 p reads queue right behind this
        p_h[l] = __builtin_bit_cast(unsigned int,
                                    __builtin_amdgcn_cvt_pkrtz(cur0, cur1));
        mcur = msk_s[(s + 1 < SEQ) ? s + 1 : SEQ - 1];

        // next-step scale — VALU-pipe DPP max, overlaps the LDS read latency
        mx  = wave_max_dpp(fmaxf(cur0, cur1));
        inv = __builtin_amdgcn_rcpf(256.0f * mx);
        offadd = __logf(mx) + 5.545177444479562f;

        // rotate emission pipeline (exp off the critical path)
        ex.x = __expf(em1.x) * inv;
        ex.y = __expf(em1.y) * inv;
        em1 = em2;
    }

    // ---- log_z = offset + log( sum_j P_j * exp(end_j) ) ----
    float term = cur0 * __expf(end_t[c0]) + cur1 * __expf(end_t[c1]);
    #pragma unroll
    for (int off = 32; off; off >>= 1)
        term += __shfl_xor(term, off);
    float log_z = offset + __logf(term);

    // ---- gold-path score (single wave, 16 s-iters/lane) ----
    const int tb = b * SEQ;
    float sc = 0.0f, sm = 0.0f;
    for (int s = l; s < SEQ; s += 64) {
        float m = msk_s[s];
        sm += m;
        if (s < SEQ - 1) {
            int tg  = tags[tb + s];
            int tg1 = tags[tb + s + 1];
            sc += eb[(size_t)s * NT + tg] * m;
            sc += transitions[tg * NT + tg1] * msk_s[s + 1];
        }
    }
    #pragma unroll
    for (int off = 32; off; off >>= 1) {
        sc += __shfl_xor(sc, off);
        sm += __shfl_xor(sm, off);
    }

    if (l == 0) {
        int tg0 = tags[tb];
        int tgl = tags[tb + SEQ - 1];
        sc += start_t[tg0];
        int last_ix = (int)fmaxf(sm - 1.0f, 0.0f);
        float ml = msk_s[SEQ - 1];
        sc += eb[(size_t)last_ix * NT + tgl] * ml;
        sc += end_t[tgl] * ml;
        out_per_batch[b] = log_z - sc;
    }
}

// mean over batch -> scalar output
__global__ void crf_reduce_kernel(const float* __restrict__ pb, float* __restrict__ out)
{
    float v = pb[threadIdx.x];   // 256 threads, one per batch
    #pragma unroll
    for (int off = 32; off; off >>= 1)
        v += __shfl_xor(v, off);
    __shared__ float s4[4];
    if ((threadIdx.x & 63) == 0) s4[threadIdx.x >> 6] = v;
    __syncthreads();
    if (threadIdx.x == 0)
        out[0] = (s4[0] + s4[1] + s4[2] + s4[3]) * (1.0f / 256.0f);
}

extern "C" void kernel_launch(void* const* d_in, const int* in_sizes, int n_in,
                              void* d_out, int out_size, void* d_ws, size_t ws_size,
                              hipStream_t stream) {
    const float* emissions   = (const float*)d_in[0];
    const float* masks       = (const float*)d_in[1];
    const int*   tags        = (const int*)  d_in[2];
    const float* transitions = (const float*)d_in[3];
    const float* start_t     = (const float*)d_in[4];
    const float* end_t       = (const float*)d_in[5];
    float* per_batch = (float*)d_ws;

    crf_scan_kernel<<<NB, 64, 0, stream>>>(emissions, masks, tags, transitions,
                                           start_t, end_t, per_batch);
    crf_reduce_kernel<<<1, 256, 0, stream>>>(per_batch, (float*)d_out);
}